// Round 1
// baseline (1583.261 us; speedup 1.0000x reference)
//
#include <hip/hip_runtime.h>
#include <math.h>

#define BB 2
#define SS 2048
#define DMM 1024
#define HH 16
#define DDEP 64

// ---------------------------------------------------------------------------
// Tiled fp32 GEMM: C = A[M,1024] @ W[1024,1024] + bias
// 64x64 block tile, 256 threads, 4x4 micro-tile per thread, K-tile = 16.
// HEADSPLIT=true scatters output to [B,H,S,64] (col tile == head since D=64).
// ---------------------------------------------------------------------------
template<bool HEADSPLIT>
__global__ __launch_bounds__(256)
void gemm_proj(const float* __restrict__ A, const float* __restrict__ W,
               const float* __restrict__ bias, float* __restrict__ C) {
  __shared__ float AsT[16][68];   // [k][row], +4 pad: conflict-free transpose store
  __shared__ float Bs[16][64];    // [k][col], natural
  const int tid = threadIdx.x;
  const int tx = tid & 15, ty = tid >> 4;
  const int row0 = blockIdx.x * 64;
  const int col0 = blockIdx.y * 64;
  float acc[4][4] = {};
  for (int k0 = 0; k0 < DMM; k0 += 16) {
    {
      const int r = tid >> 2;            // 0..63
      const int k4 = (tid & 3) << 2;     // 0,4,8,12
      float4 av = *(const float4*)(A + (size_t)(row0 + r) * DMM + k0 + k4);
      AsT[k4 + 0][r] = av.x; AsT[k4 + 1][r] = av.y;
      AsT[k4 + 2][r] = av.z; AsT[k4 + 3][r] = av.w;
    }
    {
      const int kr = tid >> 4;           // 0..15
      const int c4 = (tid & 15) << 2;    // 0..60
      *(float4*)&Bs[kr][c4] = *(const float4*)(W + (size_t)(k0 + kr) * DMM + col0 + c4);
    }
    __syncthreads();
#pragma unroll
    for (int k = 0; k < 16; ++k) {
      float4 a = *(const float4*)&AsT[k][ty << 2];
      float4 b = *(const float4*)&Bs[k][tx << 2];
      float av[4] = {a.x, a.y, a.z, a.w};
      float bv[4] = {b.x, b.y, b.z, b.w};
#pragma unroll
      for (int i = 0; i < 4; ++i)
#pragma unroll
        for (int j = 0; j < 4; ++j)
          acc[i][j] = fmaf(av[i], bv[j], acc[i][j]);
    }
    __syncthreads();
  }
  float4 bv4 = *(const float4*)(bias + col0 + (tx << 2));
#pragma unroll
  for (int i = 0; i < 4; ++i) {
    const int row = row0 + (ty << 2) + i;
    float4 o;
    o.x = acc[i][0] + bv4.x; o.y = acc[i][1] + bv4.y;
    o.z = acc[i][2] + bv4.z; o.w = acc[i][3] + bv4.w;
    if (HEADSPLIT) {
      const int b = row >> 11;             // row / S
      const int s = row & (SS - 1);
      float* dst = C + (((size_t)(b * HH + blockIdx.y) * SS + s) << 6) + (tx << 2);
      *(float4*)dst = o;
    } else {
      *(float4*)(C + (size_t)row * DMM + col0 + (tx << 2)) = o;
    }
  }
}

// ---------------------------------------------------------------------------
// Logits: per (bh, 64-row block): logits = qh @ kh^T / 8 + mask*(-1e9).
// Writes raw logits into attn area; tracks online-softmax (m, l) per row.
// ---------------------------------------------------------------------------
__global__ __launch_bounds__(256)
void attn_logits(const float* __restrict__ qh, const float* __restrict__ kh,
                 const float* __restrict__ mask, float* __restrict__ attn,
                 float* __restrict__ mrow, float* __restrict__ lrow) {
  __shared__ float qsT[64][68];   // [d][row]
  __shared__ float kt[64][68];    // [d][col]
  const int tid = threadIdx.x;
  const int tx = tid & 15, ty = tid >> 4;
  const int rb = blockIdx.x;      // 0..31  q-row block
  const int bh = blockIdx.y;      // 0..31  (b*H + h)
  const int b = bh >> 4;
  const float* qbase = qh + (((size_t)bh * SS + rb * 64) << 6);
#pragma unroll
  for (int l = 0; l < 4; ++l) {
    const int f = tid + l * 256;           // 0..1023 float4 slots
    const int r = f >> 4;
    const int d4 = (f & 15) << 2;
    float4 v = *(const float4*)(qbase + (r << 6) + d4);
    qsT[d4 + 0][r] = v.x; qsT[d4 + 1][r] = v.y;
    qsT[d4 + 2][r] = v.z; qsT[d4 + 3][r] = v.w;
  }
  float mt[4], lt[4];
#pragma unroll
  for (int i = 0; i < 4; ++i) { mt[i] = -1e30f; lt[i] = 0.f; }
  __syncthreads();
  for (int cb = 0; cb < 32; ++cb) {
    const float* kbase = kh + (((size_t)bh * SS + cb * 64) << 6);
#pragma unroll
    for (int l = 0; l < 4; ++l) {
      const int f = tid + l * 256;
      const int r = f >> 4;
      const int d4 = (f & 15) << 2;
      float4 v = *(const float4*)(kbase + (r << 6) + d4);
      kt[d4 + 0][r] = v.x; kt[d4 + 1][r] = v.y;
      kt[d4 + 2][r] = v.z; kt[d4 + 3][r] = v.w;
    }
    __syncthreads();
    float acc[4][4] = {};
#pragma unroll 8
    for (int d = 0; d < 64; ++d) {
      float4 a = *(const float4*)&qsT[d][ty << 2];
      float4 bb = *(const float4*)&kt[d][tx << 2];
      float av[4] = {a.x, a.y, a.z, a.w};
      float bvv[4] = {bb.x, bb.y, bb.z, bb.w};
#pragma unroll
      for (int i = 0; i < 4; ++i)
#pragma unroll
        for (int j = 0; j < 4; ++j)
          acc[i][j] = fmaf(av[i], bvv[j], acc[i][j]);
    }
    float4 mk = *(const float4*)(mask + (size_t)b * SS + cb * 64 + (tx << 2));
    const float mb0 = mk.x * -1e9f, mb1 = mk.y * -1e9f;
    const float mb2 = mk.z * -1e9f, mb3 = mk.w * -1e9f;
#pragma unroll
    for (int i = 0; i < 4; ++i) {
      float x0 = acc[i][0] * 0.125f + mb0;
      float x1 = acc[i][1] * 0.125f + mb1;
      float x2 = acc[i][2] * 0.125f + mb2;
      float x3 = acc[i][3] * 0.125f + mb3;
      const int row = rb * 64 + (ty << 2) + i;
      float4 o = {x0, x1, x2, x3};
      *(float4*)(attn + ((size_t)bh * SS + row) * SS + cb * 64 + (tx << 2)) = o;
      float mx = fmaxf(fmaxf(x0, x1), fmaxf(x2, x3));
      float mn = fmaxf(mt[i], mx);
      lt[i] = lt[i] * __expf(mt[i] - mn) +
              __expf(x0 - mn) + __expf(x1 - mn) + __expf(x2 - mn) + __expf(x3 - mn);
      mt[i] = mn;
    }
    __syncthreads();
  }
  // combine (m,l) across the 16 tx lanes holding each row
#pragma unroll
  for (int i = 0; i < 4; ++i) {
    float m = mt[i], l = lt[i];
#pragma unroll
    for (int off = 1; off < 16; off <<= 1) {
      float mo = __shfl_xor(m, off, 64);
      float lo = __shfl_xor(l, off, 64);
      float mn = fmaxf(m, mo);
      l = l * __expf(m - mn) + lo * __expf(mo - mn);
      m = mn;
    }
    if (tx == 0) {
      const int r = rb * 64 + (ty << 2) + i;
      mrow[(size_t)bh * SS + r] = m;
      lrow[(size_t)bh * SS + r] = l;
    }
  }
}

// ---------------------------------------------------------------------------
// PV: re-read logits, finalize attn = exp(x-m)/l (write back = output 1),
// fuse ctx = attn @ vh into merged [B,S,DM] layout.
// ---------------------------------------------------------------------------
__global__ __launch_bounds__(256)
void attn_pv(const float* __restrict__ vh, const float* __restrict__ mrow,
             const float* __restrict__ lrow, float* __restrict__ attn,
             float* __restrict__ ctx) {
  __shared__ float pT[64][68];    // [col][row]
  __shared__ float vs[64][64];    // [col][d]
  __shared__ float ms[64], rls[64];
  const int tid = threadIdx.x;
  const int tx = tid & 15, ty = tid >> 4;
  const int rb = blockIdx.x, bh = blockIdx.y;
  const int b = bh >> 4, h = bh & 15;
  if (tid < 64) {
    const int r = rb * 64 + tid;
    ms[tid] = mrow[(size_t)bh * SS + r];
    rls[tid] = 1.f / lrow[(size_t)bh * SS + r];
  }
  __syncthreads();
  float acc[4][4] = {};
  float* arow = attn + ((size_t)bh * SS + rb * 64) * SS;
  for (int cb = 0; cb < 32; ++cb) {
    const float* vbase = vh + (((size_t)bh * SS + cb * 64) << 6);
#pragma unroll
    for (int l = 0; l < 4; ++l) {
      const int f = tid + l * 256;
      const int r = f >> 4;
      const int d4 = (f & 15) << 2;
      *(float4*)&vs[r][d4] = *(const float4*)(vbase + (r << 6) + d4);
    }
#pragma unroll
    for (int l = 0; l < 4; ++l) {
      const int f = tid + l * 256;
      const int r = f >> 4;
      const int c4 = (f & 15) << 2;
      float* ap = arow + (size_t)r * SS + cb * 64 + c4;
      float4 x = *(const float4*)ap;
      const float mm = ms[r], rl = rls[r];
      float4 p;
      p.x = __expf(x.x - mm) * rl;
      p.y = __expf(x.y - mm) * rl;
      p.z = __expf(x.z - mm) * rl;
      p.w = __expf(x.w - mm) * rl;
      *(float4*)ap = p;                 // final attn output
      pT[c4 + 0][r] = p.x; pT[c4 + 1][r] = p.y;
      pT[c4 + 2][r] = p.z; pT[c4 + 3][r] = p.w;
    }
    __syncthreads();
#pragma unroll 8
    for (int c = 0; c < 64; ++c) {
      float4 a = *(const float4*)&pT[c][ty << 2];
      float4 bb = *(const float4*)&vs[c][tx << 2];
      float av[4] = {a.x, a.y, a.z, a.w};
      float bvv[4] = {bb.x, bb.y, bb.z, bb.w};
#pragma unroll
      for (int i = 0; i < 4; ++i)
#pragma unroll
        for (int j = 0; j < 4; ++j)
          acc[i][j] = fmaf(av[i], bvv[j], acc[i][j]);
    }
    __syncthreads();
  }
#pragma unroll
  for (int i = 0; i < 4; ++i) {
    const int s = rb * 64 + (ty << 2) + i;
    float4 o = {acc[i][0], acc[i][1], acc[i][2], acc[i][3]};
    *(float4*)(ctx + ((size_t)b * SS + s) * DMM + h * 64 + (tx << 2)) = o;
  }
}

// ---------------------------------------------------------------------------
extern "C" void kernel_launch(void* const* d_in, const int* in_sizes, int n_in,
                              void* d_out, int out_size, void* d_ws, size_t ws_size,
                              hipStream_t stream) {
  const float* q    = (const float*)d_in[0];
  const float* k    = (const float*)d_in[1];
  const float* v    = (const float*)d_in[2];
  const float* mask = (const float*)d_in[3];
  const float* Wq   = (const float*)d_in[4];
  const float* bq   = (const float*)d_in[5];
  const float* Wk   = (const float*)d_in[6];
  const float* bk   = (const float*)d_in[7];
  const float* Wv   = (const float*)d_in[8];
  const float* bvp  = (const float*)d_in[9];
  const float* Wo   = (const float*)d_in[10];
  const float* bo   = (const float*)d_in[11];

  float* out  = (float*)d_out;                          // [B,S,DM]
  float* attn = out + (size_t)BB * SS * DMM;            // [B,H,S,S]

  float* ws   = (float*)d_ws;
  const size_t PROJ = (size_t)BB * HH * SS * DDEP;      // 4,194,304
  float* qh   = ws;
  float* kh   = qh + PROJ;
  float* vhh  = kh + PROJ;
  float* ctx  = vhh + PROJ;
  float* mrow = ctx + PROJ;
  float* lrow = mrow + (size_t)BB * HH * SS;

  dim3 blk(256);
  dim3 g1(64, 16);   // 4096/64 row tiles x 1024/64 col tiles
  hipLaunchKernelGGL((gemm_proj<true>),  g1, blk, 0, stream, q, Wq, bq,  qh);
  hipLaunchKernelGGL((gemm_proj<true>),  g1, blk, 0, stream, k, Wk, bk,  kh);
  hipLaunchKernelGGL((gemm_proj<true>),  g1, blk, 0, stream, v, Wv, bvp, vhh);
  dim3 g2(32, 32);   // 32 row-blocks x 32 (b,h)
  hipLaunchKernelGGL(attn_logits, g2, blk, 0, stream, qh, kh, mask, attn, mrow, lrow);
  hipLaunchKernelGGL(attn_pv,     g2, blk, 0, stream, vhh, mrow, lrow, attn, ctx);
  hipLaunchKernelGGL((gemm_proj<false>), g1, blk, 0, stream, ctx, Wo, bo, out);
}